// Round 3
// baseline (486.136 us; speedup 1.0000x reference)
//
#include <hip/hip_runtime.h>
#include <hip/hip_bf16.h>
#include <stdint.h>
#include <stddef.h>

// SimpleStateSpaceModel: B=4, S=4096, D=1024. FP32 inputs/output (per reference);
// bf16 MFMA internally (no fp32 MFMA on CDNA4).
// Pipeline (68 MB of d_ws):
//   K1 gemm_bt<f32->bf16> : P[m,0:1024]=x@dt_w^T, P[m,1024:2048]=x@B_w^T
//   K2 fuse_gates         : IN-PLACE P -> gate | inp   (x,dt_b,A_log,h0 read fp32)
//   K3 scan_sum           : per-(b,d,chunk) gate-product + local scan tail
//   K4 scan_carry         : sequential combine over 128 chunks (carry -> Pc)
//   K5 scan_apply         : local scan w/ carry-in, h overwrites gate slot of P
//   K6 gemm_bt<bf16->f32> : out = h@C_w^T + D*x (fp32 epilogue + fp32 store)

#define Bdim 4
#define Sdim 4096
#define Dd   1024
#define Mdim (Bdim * Sdim)      // 16384
#define CCH  128                // scan chunks per sequence
#define LCH  (Sdim / CCH)       // 32 steps per chunk

typedef __attribute__((ext_vector_type(8))) short  short8;
typedef __attribute__((ext_vector_type(4))) float  floatx4;

__device__ __forceinline__ float b2f(short v) {
  unsigned u = ((unsigned)(unsigned short)v) << 16;
  float f; __builtin_memcpy(&f, &u, 4); return f;
}
__device__ __forceinline__ short f2b(float f) {
  unsigned u; __builtin_memcpy(&u, &f, 4);
  u += 0x7fffu + ((u >> 16) & 1u);   // round-to-nearest-even
  return (short)(u >> 16);
}

// 8-element loader -> bf16x8. AT=short: direct; AT=float: load 2x float4 + RNE cvt.
template <typename AT>
__device__ __forceinline__ short8 ld8(const AT* p);
template <>
__device__ __forceinline__ short8 ld8<short>(const short* p) {
  return *(const short8*)p;
}
template <>
__device__ __forceinline__ short8 ld8<float>(const float* p) {
  floatx4 lo = *(const floatx4*)p;
  floatx4 hi = *(const floatx4*)(p + 4);
  short8 r;
  r[0] = f2b(lo[0]); r[1] = f2b(lo[1]); r[2] = f2b(lo[2]); r[3] = f2b(lo[3]);
  r[4] = f2b(hi[0]); r[5] = f2b(hi[1]); r[6] = f2b(hi[2]); r[7] = f2b(hi[3]);
  return r;
}

__device__ __forceinline__ void st_out(short* p, float v) { *p = f2b(v); }
__device__ __forceinline__ void st_out(float* p, float v) { *p = v; }

// ---------------------------------------------------------------------------
// B^T GEMM: Out[m,n] = sum_k A[m,k] * W[n,k]   (W fp32 row-major [N][K])
// A is AT (fp32 or bf16), row stride lda elems. Out is OT, row stride ldo.
// 128x128 tile, BK=32, 4 waves (2x2), each wave 64x64 via 4x4 of 16x16x32 MFMA.
// W is a virtual row-concat of W0 (rows < nsplit) and W1 (rows >= nsplit).
// Optional fused epilogue: Out += Dp[n] * Xr[m*ldx + n]  (fp32).
// ---------------------------------------------------------------------------
template <typename AT, typename OT>
__global__ __launch_bounds__(256) void gemm_bt(
    const AT* __restrict__ A, int lda,
    const float* __restrict__ W0, const float* __restrict__ W1, int nsplit,
    OT* __restrict__ Out, int ldo, int K,
    const float* __restrict__ Dp, const float* __restrict__ Xr, int ldx)
{
  __shared__ short As[128 * 32];
  __shared__ short Ws[128 * 32];

  const int tid = threadIdx.x;
  const int m0 = blockIdx.x * 128;
  const int n0 = blockIdx.y * 128;
  const float* Wp = (n0 < nsplit) ? (W0 + (size_t)n0 * K)
                                  : (W1 + (size_t)(n0 - nsplit) * K);
  const AT* Ap = A + (size_t)m0 * lda;

  const int lane = tid & 63;
  const int wv   = tid >> 6;
  const int wm   = (wv & 1) * 64;
  const int wn   = (wv >> 1) * 64;
  const int quad = lane >> 4;
  const int l16  = lane & 15;

  floatx4 acc[4][4] = {};

  // staging: 512 chunks of 8 elems per tile; thread handles chunks {tid, tid+256}
  const int c0 = tid, c1 = tid + 256;
  const size_t gaA0 = (size_t)(c0 >> 2) * lda + (size_t)(c0 & 3) * 8;
  const size_t gaA1 = (size_t)(c1 >> 2) * lda + (size_t)(c1 & 3) * 8;
  const size_t gaW0 = (size_t)(c0 >> 2) * K   + (size_t)(c0 & 3) * 8;
  const size_t gaW1 = (size_t)(c1 >> 2) * K   + (size_t)(c1 & 3) * 8;

  for (int k0 = 0; k0 < K; k0 += 32) {
    short8 a0 = ld8<AT>(Ap + gaA0 + k0);
    short8 a1 = ld8<AT>(Ap + gaA1 + k0);
    short8 b0 = ld8<float>(Wp + gaW0 + k0);
    short8 b1 = ld8<float>(Wp + gaW1 + k0);
    __syncthreads();                       // protect previous iter's LDS reads
    *(short8*)(As + c0 * 8) = a0;          // row-major [128][32]: chunk c at c*8
    *(short8*)(As + c1 * 8) = a1;
    *(short8*)(Ws + c0 * 8) = b0;
    *(short8*)(Ws + c1 * 8) = b1;
    __syncthreads();

    short8 af[4], wf[4];
#pragma unroll
    for (int i = 0; i < 4; i++)   // A-frag: A[m = l16][k = quad*8 + j]
      af[i] = *(const short8*)(As + (wm + i * 16 + l16) * 32 + quad * 8);
#pragma unroll
    for (int i = 0; i < 4; i++)   // B-frag: B[k = quad*8 + j][n = l16] == W[n][k..]
      wf[i] = *(const short8*)(Ws + (wn + i * 16 + l16) * 32 + quad * 8);
#pragma unroll
    for (int mt = 0; mt < 4; mt++)
#pragma unroll
      for (int nt = 0; nt < 4; nt++)
        acc[mt][nt] = __builtin_amdgcn_mfma_f32_16x16x32_bf16(
            af[mt], wf[nt], acc[mt][nt], 0, 0, 0);
  }

  // C/D layout: row = quad*4 + r, col = l16  [verified m89/m91]
#pragma unroll
  for (int mt = 0; mt < 4; mt++) {
#pragma unroll
    for (int nt = 0; nt < 4; nt++) {
#pragma unroll
      for (int r = 0; r < 4; r++) {
        int m = m0 + wm + mt * 16 + quad * 4 + r;
        int n = n0 + wn + nt * 16 + l16;
        float v = acc[mt][nt][r];
        if (Dp) v += Dp[n] * Xr[(size_t)m * ldx + n];
        st_out(Out + (size_t)m * ldo + n, v);
      }
    }
  }
}

// ---------------------------------------------------------------------------
// K2: elementwise gate/input computation, IN PLACE over P (bf16).
// P row = [dt_pre(1024) | Bp(1024)]  ->  [gate(1024) | inp(1024)]
// x, dt_b, A_log, h0 are fp32.
// ---------------------------------------------------------------------------
__global__ __launch_bounds__(256) void fuse_gates(
    short* __restrict__ P, const float* __restrict__ x,
    const float* __restrict__ dt_b, const float* __restrict__ A_log,
    const float* __restrict__ h0)
{
  const int i8 = blockIdx.x * 256 + threadIdx.x;   // 2,097,152 total
  const int m  = i8 >> 7;                          // row (b*S + s)
  const int e0 = (i8 & 127) * 8;
  const int s  = m & (Sdim - 1);
  const int b  = m >> 12;

  short8 dp = *(const short8*)(P + (size_t)m * 2048 + e0);
  short8 bp = *(const short8*)(P + (size_t)m * 2048 + 1024 + e0);
  floatx4 xv0 = *(const floatx4*)(x + (size_t)m * Dd + e0);
  floatx4 xv1 = *(const floatx4*)(x + (size_t)m * Dd + e0 + 4);
  floatx4 db0 = *(const floatx4*)(dt_b + e0);
  floatx4 db1 = *(const floatx4*)(dt_b + e0 + 4);
  floatx4 al0 = *(const floatx4*)(A_log + e0);
  floatx4 al1 = *(const floatx4*)(A_log + e0 + 4);
  short8 gv, iv;
#pragma unroll
  for (int j = 0; j < 8; j++) {
    float xj = (j < 4) ? xv0[j & 3] : xv1[j & 3];
    float dbj = (j < 4) ? db0[j & 3] : db1[j & 3];
    float alj = (j < 4) ? al0[j & 3] : al1[j & 3];
    float z  = b2f(dp[j]) + dbj;
    float sp = fmaxf(z, 0.f) + log1pf(expf(-fabsf(z)));  // softplus, stable
    float nA = -expf(alj);
    float g  = expf(sp * nA);
    float u  = sp * b2f(bp[j]) * xj;
    if (s == 0) u += g * h0[b * Dd + e0 + j];            // fold h0 into step 1
    gv[j] = f2b(g);
    iv[j] = f2b(u);
  }
  *(short8*)(P + (size_t)m * 2048 + e0)        = gv;
  *(short8*)(P + (size_t)m * 2048 + 1024 + e0) = iv;
}

// ---------------------------------------------------------------------------
// K3: per-chunk summaries from P: Pc = prod(g), Hl = local scan tail.
// grid (Dd/256, CCH, Bdim), block 256; thread handles one (b, d, chunk).
// ---------------------------------------------------------------------------
__global__ __launch_bounds__(256) void scan_sum(
    const short* __restrict__ P, float* __restrict__ Pc, float* __restrict__ Hl)
{
  const int d = blockIdx.x * 256 + threadIdx.x;
  const int c = blockIdx.y;
  const int b = blockIdx.z;
  size_t base = ((size_t)b * Sdim + (size_t)c * LCH) * 2048 + d;
  float p = 1.f, h = 0.f;
#pragma unroll 4
  for (int t = 0; t < LCH; t++) {
    float g = b2f(P[base + (size_t)t * 2048]);
    float u = b2f(P[base + (size_t)t * 2048 + 1024]);
    h = g * h + u;
    p *= g;
  }
  size_t o = ((size_t)b * CCH + c) * Dd + d;
  Pc[o] = p;
  Hl[o] = h;
}

// ---------------------------------------------------------------------------
// K4: sequential carry across chunks per (b,d) chain (4096 chains x 128).
// Carry-in for chunk c overwrites Pc[c] (read-then-write, same thread).
// ---------------------------------------------------------------------------
__global__ __launch_bounds__(256) void scan_carry(
    float* __restrict__ Pc, const float* __restrict__ Hl)
{
  const int t = blockIdx.x * 256 + threadIdx.x;  // 4096 threads
  const int b = t >> 10;
  const int d = t & 1023;
  float st = 0.f;                                // h0 already folded into inputs
  for (int c = 0; c < CCH; c++) {
    size_t o = ((size_t)b * CCH + c) * Dd + d;
    float p = Pc[o], h = Hl[o];
    Pc[o] = st;                                  // carry-in for this chunk
    st = p * st + h;
  }
}

// ---------------------------------------------------------------------------
// K5: redo local scan with carry-in; h (bf16) overwrites the gate slot of P.
// ---------------------------------------------------------------------------
__global__ __launch_bounds__(256) void scan_apply(
    short* __restrict__ P, const float* __restrict__ carry)
{
  const int d = blockIdx.x * 256 + threadIdx.x;
  const int c = blockIdx.y;
  const int b = blockIdx.z;
  size_t base = ((size_t)b * Sdim + (size_t)c * LCH) * 2048 + d;
  float h = carry[((size_t)b * CCH + c) * Dd + d];
#pragma unroll 4
  for (int t = 0; t < LCH; t++) {
    size_t o = base + (size_t)t * 2048;
    float g = b2f(P[o]);
    float u = b2f(P[o + 1024]);
    h = g * h + u;
    P[o] = f2b(h);                               // h over gate slot
  }
}

// ---------------------------------------------------------------------------
extern "C" void kernel_launch(void* const* d_in, const int* in_sizes, int n_in,
                              void* d_out, int out_size, void* d_ws, size_t ws_size,
                              hipStream_t stream)
{
  const float* x     = (const float*)d_in[0];  // [4,4096,1024] fp32
  const float* h0    = (const float*)d_in[1];  // [4,1024]
  const float* dt_w  = (const float*)d_in[2];  // [1024,1024]
  const float* dt_b  = (const float*)d_in[3];  // [1024]
  const float* A_log = (const float*)d_in[4];  // [1024]
  const float* B_w   = (const float*)d_in[5];  // [1024,1024]
  const float* C_w   = (const float*)d_in[6];  // [1024,1024]
  const float* Dp    = (const float*)d_in[7];  // [1024]
  float* out = (float*)d_out;                  // [4,4096,1024] fp32

  // workspace layout (68 MB total):
  //   [0,64MB)    P bf16 [16384][2048]: dt_pre|Bp -> gate|inp -> h|inp
  //   [64,66MB)   Pc fp32 [4][128][1024] (chunk gate-products, then carries)
  //   [66,68MB)   Hl fp32 [4][128][1024] (chunk local-scan tails)
  char* ws = (char*)d_ws;
  short* P  = (short*)(ws);
  float* Pc = (float*)(ws + ((size_t)64 << 20));
  float* Hl = (float*)(ws + ((size_t)66 << 20));

  // K1: P = x @ [dt_w; B_w]^T   (M=16384, N=2048, K=1024), fp32 A -> bf16 out
  gemm_bt<float, short><<<dim3(Mdim / 128, 2048 / 128), 256, 0, stream>>>(
      x, Dd, dt_w, B_w, 1024, P, 2048, 1024, nullptr, nullptr, 0);

  // K2: gate/inputs in place over P
  fuse_gates<<<(Mdim * (Dd / 8)) / 256, 256, 0, stream>>>(P, x, dt_b, A_log, h0);

  // K3-K5: chunked scan (h lands in P's gate slot)
  scan_sum<<<dim3(Dd / 256, CCH, Bdim), 256, 0, stream>>>(P, Pc, Hl);
  scan_carry<<<(Bdim * Dd) / 256, 256, 0, stream>>>(Pc, Hl);
  scan_apply<<<dim3(Dd / 256, CCH, Bdim), 256, 0, stream>>>(P, Pc);

  // K6: out = h @ C_w^T + D*x  (M=16384, N=1024, K=1024; h bf16 in P, lda=2048)
  gemm_bt<short, float><<<dim3(Mdim / 128, 1024 / 128), 256, 0, stream>>>(
      P, 2048, C_w, C_w, 2048, out, Dd, 1024, Dp, x, Dd);
}

// Round 4
// 446.821 us; speedup vs baseline: 1.0880x; 1.0880x over previous
//
#include <hip/hip_runtime.h>
#include <hip/hip_bf16.h>
#include <stdint.h>
#include <stddef.h>

// SimpleStateSpaceModel: B=4, S=4096, D=1024. FP32 in/out; bf16 MFMA inside.
// FULL path (ws >= 106MB):
//   C0 cast_x / cast_w     : x->xb (bf16, 32MB), {dt_w,B_w,C_w}->wcat (bf16, 6MB)
//   K1 gemm_async<bf16out> : P[m,0:1024]=x@dt_w^T, P[m,1024:2048]=x@B_w^T
//   K3 scan_sum2           : recompute gate/inp from (P,x); chunk Pc/Hl
//   K4 scan_carry4         : sequential combine over 128 chunks (carry -> Pc)
//   K5 scan_apply2         : recompute + local scan w/ carry-in; h -> P cols 0:1024
//   K6 gemm_async<f32out>  : out = h@C_w^T + D*x
// SAFE path (ws >= 68MB): same but gemm_bt (VALU-convert staging, R3-verified).

#define Bdim 4
#define Sdim 4096
#define Dd   1024
#define Mdim (Bdim * Sdim)      // 16384
#define CCH  128                // scan chunks per sequence
#define LCH  (Sdim / CCH)       // 32 steps per chunk

typedef __attribute__((ext_vector_type(8))) short  short8;
typedef __attribute__((ext_vector_type(4))) short  short4v;
typedef __attribute__((ext_vector_type(4))) float  floatx4;

__device__ __forceinline__ float b2f(short v) {
  unsigned u = ((unsigned)(unsigned short)v) << 16;
  float f; __builtin_memcpy(&f, &u, 4); return f;
}
__device__ __forceinline__ short f2b(float f) {
  unsigned u; __builtin_memcpy(&u, &f, 4);
  u += 0x7fffu + ((u >> 16) & 1u);   // round-to-nearest-even
  return (short)(u >> 16);
}

template <typename AT>
__device__ __forceinline__ short8 ld8(const AT* p);
template <>
__device__ __forceinline__ short8 ld8<short>(const short* p) {
  return *(const short8*)p;
}
template <>
__device__ __forceinline__ short8 ld8<float>(const float* p) {
  floatx4 lo = *(const floatx4*)p;
  floatx4 hi = *(const floatx4*)(p + 4);
  short8 r;
  r[0] = f2b(lo[0]); r[1] = f2b(lo[1]); r[2] = f2b(lo[2]); r[3] = f2b(lo[3]);
  r[4] = f2b(hi[0]); r[5] = f2b(hi[1]); r[6] = f2b(hi[2]); r[7] = f2b(hi[3]);
  return r;
}

__device__ __forceinline__ void st_out(short* p, float v) { *p = f2b(v); }
__device__ __forceinline__ void st_out(float* p, float v) { *p = v; }

// async 16B global->LDS (DMA, no VGPR round-trip). lds dest must be
// wave-uniform; lane i's data lands at l + i*16. [m97 pattern]
__device__ __forceinline__ void cp16(const void* g, void* l) {
  __builtin_amdgcn_global_load_lds(
      (__attribute__((address_space(1))) void*)g,
      (__attribute__((address_space(3))) void*)l, 16, 0, 0);
}

// ---------------------------------------------------------------------------
// FULL-path GEMM: Out[m,n] = sum_k A[m,k]*W[n,k], A/W bf16, async staging.
// 128x128 tile, BK=32, 4 waves, 4x4 of 16x16x32 MFMA per wave.
// ---------------------------------------------------------------------------
template <typename OT, bool FUSE>
__global__ __launch_bounds__(256) void gemm_async(
    const short* __restrict__ A, int lda,
    const short* __restrict__ W,           // bf16 [N][K] row-major
    OT* __restrict__ Out, int ldo, int K,
    const float* __restrict__ Dp, const float* __restrict__ Xr, int ldx)
{
  __shared__ short As[128 * 32];
  __shared__ short Ws[128 * 32];

  const int tid = threadIdx.x;
  const int m0 = blockIdx.x * 128;
  const int n0 = blockIdx.y * 128;
  const short* Ap = A + (size_t)m0 * lda;
  const short* Wp = W + (size_t)n0 * K;

  const int lane = tid & 63;
  const int wv   = tid >> 6;
  const int wm   = (wv & 1) * 64;
  const int wn   = (wv >> 1) * 64;
  const int quad = lane >> 4;
  const int l16  = lane & 15;

  floatx4 acc[4][4] = {};

  // chunk c (16B of 8 bf16) lives at LDS offset c*16; covers row c>>2, cols
  // (c&3)*8.. of the [128][32] tile. Wave wv issues chunks [wv*128, wv*128+128).
  const int cb  = wv * 128;
  const int cA0 = cb + lane, cA1 = cb + 64 + lane;
  const size_t gA0 = (size_t)(cA0 >> 2) * lda + (size_t)(cA0 & 3) * 8;
  const size_t gA1 = (size_t)(cA1 >> 2) * lda + (size_t)(cA1 & 3) * 8;
  const size_t gW0 = (size_t)(cA0 >> 2) * K   + (size_t)(cA0 & 3) * 8;
  const size_t gW1 = (size_t)(cA1 >> 2) * K   + (size_t)(cA1 & 3) * 8;

  for (int k0 = 0; k0 < K; k0 += 32) {
    __syncthreads();                    // prior iter's ds_reads complete
    cp16(Ap + gA0 + k0, As + (size_t)cb * 8);
    cp16(Ap + gA1 + k0, As + (size_t)(cb + 64) * 8);
    cp16(Wp + gW0 + k0, Ws + (size_t)cb * 8);
    cp16(Wp + gW1 + k0, Ws + (size_t)(cb + 64) * 8);
    __syncthreads();                    // drains vmcnt(0): LDS data visible

    short8 af[4], wf[4];
#pragma unroll
    for (int i = 0; i < 4; i++)   // A-frag: A[m = l16][k = quad*8 + j]
      af[i] = *(const short8*)(As + (wm + i * 16 + l16) * 32 + quad * 8);
#pragma unroll
    for (int i = 0; i < 4; i++)   // B-frag: W[n = l16][k = quad*8 + j]
      wf[i] = *(const short8*)(Ws + (wn + i * 16 + l16) * 32 + quad * 8);
#pragma unroll
    for (int mt = 0; mt < 4; mt++)
#pragma unroll
      for (int nt = 0; nt < 4; nt++)
        acc[mt][nt] = __builtin_amdgcn_mfma_f32_16x16x32_bf16(
            af[mt], wf[nt], acc[mt][nt], 0, 0, 0);
  }

  // C/D layout: row = quad*4 + r, col = l16  [verified m89/m91]
#pragma unroll
  for (int mt = 0; mt < 4; mt++) {
#pragma unroll
    for (int nt = 0; nt < 4; nt++) {
#pragma unroll
      for (int r = 0; r < 4; r++) {
        int m = m0 + wm + mt * 16 + quad * 4 + r;
        int n = n0 + wn + nt * 16 + l16;
        float v = acc[mt][nt][r];
        if (FUSE) v += Dp[n] * Xr[(size_t)m * ldx + n];
        st_out(Out + (size_t)m * ldo + n, v);
      }
    }
  }
}

// ---------------------------------------------------------------------------
// SAFE-path GEMM (R3-verified): fp32/bf16 A, fp32 W, VALU-convert staging.
// ---------------------------------------------------------------------------
template <typename AT, typename OT>
__global__ __launch_bounds__(256) void gemm_bt(
    const AT* __restrict__ A, int lda,
    const float* __restrict__ W0, const float* __restrict__ W1, int nsplit,
    OT* __restrict__ Out, int ldo, int K,
    const float* __restrict__ Dp, const float* __restrict__ Xr, int ldx)
{
  __shared__ short As[128 * 32];
  __shared__ short Ws[128 * 32];

  const int tid = threadIdx.x;
  const int m0 = blockIdx.x * 128;
  const int n0 = blockIdx.y * 128;
  const float* Wp = (n0 < nsplit) ? (W0 + (size_t)n0 * K)
                                  : (W1 + (size_t)(n0 - nsplit) * K);
  const AT* Ap = A + (size_t)m0 * lda;

  const int lane = tid & 63;
  const int wv   = tid >> 6;
  const int wm   = (wv & 1) * 64;
  const int wn   = (wv >> 1) * 64;
  const int quad = lane >> 4;
  const int l16  = lane & 15;

  floatx4 acc[4][4] = {};

  const int c0 = tid, c1 = tid + 256;
  const size_t gaA0 = (size_t)(c0 >> 2) * lda + (size_t)(c0 & 3) * 8;
  const size_t gaA1 = (size_t)(c1 >> 2) * lda + (size_t)(c1 & 3) * 8;
  const size_t gaW0 = (size_t)(c0 >> 2) * K   + (size_t)(c0 & 3) * 8;
  const size_t gaW1 = (size_t)(c1 >> 2) * K   + (size_t)(c1 & 3) * 8;

  for (int k0 = 0; k0 < K; k0 += 32) {
    short8 a0 = ld8<AT>(Ap + gaA0 + k0);
    short8 a1 = ld8<AT>(Ap + gaA1 + k0);
    short8 b0 = ld8<float>(Wp + gaW0 + k0);
    short8 b1 = ld8<float>(Wp + gaW1 + k0);
    __syncthreads();
    *(short8*)(As + c0 * 8) = a0;
    *(short8*)(As + c1 * 8) = a1;
    *(short8*)(Ws + c0 * 8) = b0;
    *(short8*)(Ws + c1 * 8) = b1;
    __syncthreads();

    short8 af[4], wf[4];
#pragma unroll
    for (int i = 0; i < 4; i++)
      af[i] = *(const short8*)(As + (wm + i * 16 + l16) * 32 + quad * 8);
#pragma unroll
    for (int i = 0; i < 4; i++)
      wf[i] = *(const short8*)(Ws + (wn + i * 16 + l16) * 32 + quad * 8);
#pragma unroll
    for (int mt = 0; mt < 4; mt++)
#pragma unroll
      for (int nt = 0; nt < 4; nt++)
        acc[mt][nt] = __builtin_amdgcn_mfma_f32_16x16x32_bf16(
            af[mt], wf[nt], acc[mt][nt], 0, 0, 0);
  }

#pragma unroll
  for (int mt = 0; mt < 4; mt++) {
#pragma unroll
    for (int nt = 0; nt < 4; nt++) {
#pragma unroll
      for (int r = 0; r < 4; r++) {
        int m = m0 + wm + mt * 16 + quad * 4 + r;
        int n = n0 + wn + nt * 16 + l16;
        float v = acc[mt][nt][r];
        if (Dp) v += Dp[n] * Xr[(size_t)m * ldx + n];
        st_out(Out + (size_t)m * ldo + n, v);
      }
    }
  }
}

// ---------------------------------------------------------------------------
// Cast kernels: fp32 -> bf16, 8 elems/thread.
// ---------------------------------------------------------------------------
__global__ __launch_bounds__(256) void cast_f32_bf16(
    const float* __restrict__ src, short* __restrict__ dst)
{
  size_t i = ((size_t)blockIdx.x * 256 + threadIdx.x) * 8;
  *(short8*)(dst + i) = ld8<float>(src + i);
}

// ---------------------------------------------------------------------------
// Gate/input recompute helper: z = dt_pre + dt_b; sp = softplus(z);
// g = exp(sp * -exp(A_log)); u = sp * Bp * x.
// ---------------------------------------------------------------------------
__device__ __forceinline__ void gate_in(float dtp, float db, float nA,
                                        float bp, float xv,
                                        float& g, float& u) {
  float z  = dtp + db;
  float sp = fmaxf(z, 0.f) + log1pf(expf(-fabsf(z)));
  g = expf(sp * nA);
  u = sp * bp * xv;
}

// ---------------------------------------------------------------------------
// K3: chunk summaries, recomputing gates from P = [dt_pre | Bp] and fp32 x.
// grid 512 blocks (b*128+c), block 256; thread owns 4 consecutive d.
// ---------------------------------------------------------------------------
__global__ __launch_bounds__(256) void scan_sum2(
    const short* __restrict__ P, const float* __restrict__ x,
    const float* __restrict__ dt_b, const float* __restrict__ A_log,
    const float* __restrict__ h0,
    float* __restrict__ Pc, float* __restrict__ Hl)
{
  const int b  = blockIdx.x >> 7;
  const int c  = blockIdx.x & 127;
  const int d0 = threadIdx.x * 4;

  floatx4 db = *(const floatx4*)(dt_b + d0);
  floatx4 al = *(const floatx4*)(A_log + d0);
  float nA[4], p[4] = {1.f, 1.f, 1.f, 1.f}, h[4] = {};
#pragma unroll
  for (int j = 0; j < 4; j++) nA[j] = -expf(al[j]);

  const size_t mrow = (size_t)b * Sdim + (size_t)c * LCH;
  for (int t = 0; t < LCH; t++) {
    size_t m = mrow + t;
    short4v dt8 = *(const short4v*)(P + m * 2048 + d0);
    short4v bp8 = *(const short4v*)(P + m * 2048 + 1024 + d0);
    floatx4 xv  = *(const floatx4*)(x + m * Dd + d0);
#pragma unroll
    for (int j = 0; j < 4; j++) {
      float g, u;
      gate_in(b2f(dt8[j]), db[j], nA[j], b2f(bp8[j]), xv[j], g, u);
      if (c == 0 && t == 0) u += g * h0[b * Dd + d0 + j];
      h[j] = g * h[j] + u;
      p[j] *= g;
    }
  }
  size_t o = ((size_t)b * CCH + c) * Dd + d0;
  *(floatx4*)(Pc + o) = floatx4{p[0], p[1], p[2], p[3]};
  *(floatx4*)(Hl + o) = floatx4{h[0], h[1], h[2], h[3]};
}

// ---------------------------------------------------------------------------
// K4: sequential carry over 128 chunks; carry-in overwrites Pc. 1024 threads,
// float4 per thread.
// ---------------------------------------------------------------------------
__global__ __launch_bounds__(256) void scan_carry4(
    float* __restrict__ Pc, const float* __restrict__ Hl)
{
  const int t  = blockIdx.x * 256 + threadIdx.x;   // 0..1023
  const int b  = t >> 8;
  const int d0 = (t & 255) * 4;
  floatx4 st = {};
  for (int c = 0; c < CCH; c++) {
    size_t o = ((size_t)b * CCH + c) * Dd + d0;
    floatx4 pv = *(const floatx4*)(Pc + o);
    floatx4 hv = *(const floatx4*)(Hl + o);
    *(floatx4*)(Pc + o) = st;
    st = pv * st + hv;
  }
}

// ---------------------------------------------------------------------------
// K5: local scan with carry-in, recomputing gates; h (bf16) -> P cols 0:1024.
// ---------------------------------------------------------------------------
__global__ __launch_bounds__(256) void scan_apply2(
    short* __restrict__ P, const float* __restrict__ x,
    const float* __restrict__ dt_b, const float* __restrict__ A_log,
    const float* __restrict__ h0, const float* __restrict__ carry)
{
  const int b  = blockIdx.x >> 7;
  const int c  = blockIdx.x & 127;
  const int d0 = threadIdx.x * 4;

  floatx4 db = *(const floatx4*)(dt_b + d0);
  floatx4 al = *(const floatx4*)(A_log + d0);
  float nA[4];
#pragma unroll
  for (int j = 0; j < 4; j++) nA[j] = -expf(al[j]);

  floatx4 hc = *(const floatx4*)(carry + ((size_t)b * CCH + c) * Dd + d0);
  float h[4] = {hc[0], hc[1], hc[2], hc[3]};

  const size_t mrow = (size_t)b * Sdim + (size_t)c * LCH;
  for (int t = 0; t < LCH; t++) {
    size_t m = mrow + t;
    short4v dt8 = *(const short4v*)(P + m * 2048 + d0);
    short4v bp8 = *(const short4v*)(P + m * 2048 + 1024 + d0);
    floatx4 xv  = *(const floatx4*)(x + m * Dd + d0);
    short4v hv;
#pragma unroll
    for (int j = 0; j < 4; j++) {
      float g, u;
      gate_in(b2f(dt8[j]), db[j], nA[j], b2f(bp8[j]), xv[j], g, u);
      if (c == 0 && t == 0) u += g * h0[b * Dd + d0 + j];
      h[j] = g * h[j] + u;
      hv[j] = f2b(h[j]);
    }
    *(short4v*)(P + m * 2048 + d0) = hv;   // h over dt_pre slot (own addrs)
  }
}

// ---------------------------------------------------------------------------
extern "C" void kernel_launch(void* const* d_in, const int* in_sizes, int n_in,
                              void* d_out, int out_size, void* d_ws, size_t ws_size,
                              hipStream_t stream)
{
  const float* x     = (const float*)d_in[0];  // [4,4096,1024] fp32
  const float* h0    = (const float*)d_in[1];  // [4,1024]
  const float* dt_w  = (const float*)d_in[2];  // [1024,1024]
  const float* dt_b  = (const float*)d_in[3];  // [1024]
  const float* A_log = (const float*)d_in[4];  // [1024]
  const float* B_w   = (const float*)d_in[5];  // [1024,1024]
  const float* C_w   = (const float*)d_in[6];  // [1024,1024]
  const float* Dp    = (const float*)d_in[7];  // [1024]
  float* out = (float*)d_out;                  // [4,4096,1024] fp32

  char* ws = (char*)d_ws;
  short* P  = (short*)(ws);                              // 64MB [16384][2048]
  const size_t FULL_NEED = (106ull << 20);
  const bool full = (ws_size >= FULL_NEED);

  if (full) {
    // [64,96) xb bf16; [96,102) wcat bf16 [3072][1024]; [102,104) Pc; [104,106) Hl
    short* xb   = (short*)(ws + (64ull  << 20));
    short* wcat = (short*)(ws + (96ull  << 20));
    float* Pc   = (float*)(ws + (102ull << 20));
    float* Hl   = (float*)(ws + (104ull << 20));

    cast_f32_bf16<<<(Mdim * Dd / 8) / 256, 256, 0, stream>>>(x, xb);
    cast_f32_bf16<<<(Dd * Dd / 8) / 256, 256, 0, stream>>>(dt_w, wcat);
    cast_f32_bf16<<<(Dd * Dd / 8) / 256, 256, 0, stream>>>(B_w,  wcat + 1024 * 1024);
    cast_f32_bf16<<<(Dd * Dd / 8) / 256, 256, 0, stream>>>(C_w,  wcat + 2 * 1024 * 1024);

    // K1: P = x @ [dt_w;B_w]^T  (M=16384, N=2048, K=1024)
    gemm_async<short, false><<<dim3(Mdim / 128, 16), 256, 0, stream>>>(
        xb, Dd, wcat, P, 2048, 1024, nullptr, nullptr, 0);

    scan_sum2<<<Bdim * CCH, 256, 0, stream>>>(P, x, dt_b, A_log, h0, Pc, Hl);
    scan_carry4<<<4, 256, 0, stream>>>(Pc, Hl);
    scan_apply2<<<Bdim * CCH, 256, 0, stream>>>(P, x, dt_b, A_log, h0, Pc);

    // K6: out = h @ C_w^T + D*x  (h bf16 in P, lda=2048)
    gemm_async<float, true><<<dim3(Mdim / 128, 8), 256, 0, stream>>>(
        P, 2048, wcat + 2 * 1024 * 1024, out, Dd, 1024, Dp, x, Dd);
  } else {
    // SAFE: 68MB layout, R3 GEMMs + new fused/vectorized scan
    float* Pc = (float*)(ws + (64ull << 20));
    float* Hl = (float*)(ws + (66ull << 20));

    gemm_bt<float, short><<<dim3(Mdim / 128, 16), 256, 0, stream>>>(
        x, Dd, dt_w, B_w, 1024, P, 2048, 1024, nullptr, nullptr, 0);

    scan_sum2<<<Bdim * CCH, 256, 0, stream>>>(P, x, dt_b, A_log, h0, Pc, Hl);
    scan_carry4<<<4, 256, 0, stream>>>(Pc, Hl);
    scan_apply2<<<Bdim * CCH, 256, 0, stream>>>(P, x, dt_b, A_log, h0, Pc);

    gemm_bt<short, float><<<dim3(Mdim / 128, 8), 256, 0, stream>>>(
        P, 2048, C_w, C_w, 2048, out, Dd, 1024, Dp, x, Dd);
  }
}

// Round 5
// 395.245 us; speedup vs baseline: 1.2300x; 1.1305x over previous
//
#include <hip/hip_runtime.h>
#include <hip/hip_bf16.h>
#include <stdint.h>
#include <stddef.h>

// SimpleStateSpaceModel: B=4, S=4096, D=1024. FP32 in/out; bf16 MFMA inside.
// Pipeline (exactly 106 MB of d_ws — proven available in R4):
//   C0 cast_all         : x->xb (32MB), {dt_w,B_w,C_w}->wcat (6MB)
//   K1 gemm_async<bf16> : P[m,0:1024]=x@dt_w^T, P[m,1024:2048]=x@B_w^T
//   S1 scan_local       : g,u from (P,xb); in-place P <- [hl(t) | pg(t)];
//                         chunk totals -> Pc (gate product), Hl (local tail)
//   S2 scan_carry4      : sequential combine over 128 chunks (carry -> Pc)
//   S3 scan_fix         : h(t) = hl(t) + carry*pg(t)  (chain-free, pure BW)
//   K6 gemm_async<f32>  : out = h@C_w^T + D*x (xb epilogue)

#define Bdim 4
#define Sdim 4096
#define Dd   1024
#define Mdim (Bdim * Sdim)      // 16384
#define CCH  128                // scan chunks per sequence
#define LCH  (Sdim / CCH)       // 32 steps per chunk

typedef __attribute__((ext_vector_type(8))) short  short8;
typedef __attribute__((ext_vector_type(4))) short  short4v;
typedef __attribute__((ext_vector_type(4))) float  floatx4;

__device__ __forceinline__ float b2f(short v) {
  unsigned u = ((unsigned)(unsigned short)v) << 16;
  float f; __builtin_memcpy(&f, &u, 4); return f;
}
__device__ __forceinline__ short f2b(float f) {
  unsigned u; __builtin_memcpy(&u, &f, 4);
  u += 0x7fffu + ((u >> 16) & 1u);   // round-to-nearest-even
  return (short)(u >> 16);
}

__device__ __forceinline__ short8 ld8f(const float* p) {
  floatx4 lo = *(const floatx4*)p;
  floatx4 hi = *(const floatx4*)(p + 4);
  short8 r;
  r[0] = f2b(lo[0]); r[1] = f2b(lo[1]); r[2] = f2b(lo[2]); r[3] = f2b(lo[3]);
  r[4] = f2b(hi[0]); r[5] = f2b(hi[1]); r[6] = f2b(hi[2]); r[7] = f2b(hi[3]);
  return r;
}

__device__ __forceinline__ void st_out(short* p, float v) { *p = f2b(v); }
__device__ __forceinline__ void st_out(float* p, float v) { *p = v; }

// async 16B global->LDS (DMA). lds dest wave-uniform; lane i -> l + i*16. [m97]
__device__ __forceinline__ void cp16(const void* g, void* l) {
  __builtin_amdgcn_global_load_lds(
      (__attribute__((address_space(1))) void*)g,
      (__attribute__((address_space(3))) void*)l, 16, 0, 0);
}

// ---------------------------------------------------------------------------
// GEMM: Out[m,n] = sum_k A[m,k]*W[n,k], A/W bf16, async global->LDS staging.
// 128x128 tile, BK=32, 4 waves, 4x4 of 16x16x32 MFMA per wave. [R4-verified]
// FUSE epilogue: Out += Dp[n] * b2f(Xr[m*ldx + n])   (Xr bf16)
// ---------------------------------------------------------------------------
template <typename OT, bool FUSE>
__global__ __launch_bounds__(256) void gemm_async(
    const short* __restrict__ A, int lda,
    const short* __restrict__ W,           // bf16 [N][K] row-major
    OT* __restrict__ Out, int ldo, int K,
    const float* __restrict__ Dp, const short* __restrict__ Xr, int ldx)
{
  __shared__ short As[128 * 32];
  __shared__ short Ws[128 * 32];

  const int tid = threadIdx.x;
  const int m0 = blockIdx.x * 128;
  const int n0 = blockIdx.y * 128;
  const short* Ap = A + (size_t)m0 * lda;
  const short* Wp = W + (size_t)n0 * K;

  const int lane = tid & 63;
  const int wv   = tid >> 6;
  const int wm   = (wv & 1) * 64;
  const int wn   = (wv >> 1) * 64;
  const int quad = lane >> 4;
  const int l16  = lane & 15;

  floatx4 acc[4][4] = {};

  // chunk c (16B = 8 bf16) at LDS offset c*16; covers row c>>2, cols (c&3)*8..
  const int cb  = wv * 128;
  const int cA0 = cb + lane, cA1 = cb + 64 + lane;
  const size_t gA0 = (size_t)(cA0 >> 2) * lda + (size_t)(cA0 & 3) * 8;
  const size_t gA1 = (size_t)(cA1 >> 2) * lda + (size_t)(cA1 & 3) * 8;
  const size_t gW0 = (size_t)(cA0 >> 2) * K   + (size_t)(cA0 & 3) * 8;
  const size_t gW1 = (size_t)(cA1 >> 2) * K   + (size_t)(cA1 & 3) * 8;

  for (int k0 = 0; k0 < K; k0 += 32) {
    __syncthreads();
    cp16(Ap + gA0 + k0, As + (size_t)cb * 8);
    cp16(Ap + gA1 + k0, As + (size_t)(cb + 64) * 8);
    cp16(Wp + gW0 + k0, Ws + (size_t)cb * 8);
    cp16(Wp + gW1 + k0, Ws + (size_t)(cb + 64) * 8);
    __syncthreads();

    short8 af[4], wf[4];
#pragma unroll
    for (int i = 0; i < 4; i++)   // A-frag: A[m = l16][k = quad*8 + j]
      af[i] = *(const short8*)(As + (wm + i * 16 + l16) * 32 + quad * 8);
#pragma unroll
    for (int i = 0; i < 4; i++)   // B-frag: W[n = l16][k = quad*8 + j]
      wf[i] = *(const short8*)(Ws + (wn + i * 16 + l16) * 32 + quad * 8);
#pragma unroll
    for (int mt = 0; mt < 4; mt++)
#pragma unroll
      for (int nt = 0; nt < 4; nt++)
        acc[mt][nt] = __builtin_amdgcn_mfma_f32_16x16x32_bf16(
            af[mt], wf[nt], acc[mt][nt], 0, 0, 0);
  }

  // C/D layout: row = quad*4 + r, col = l16  [verified m89/m91]
#pragma unroll
  for (int mt = 0; mt < 4; mt++) {
#pragma unroll
    for (int nt = 0; nt < 4; nt++) {
#pragma unroll
      for (int r = 0; r < 4; r++) {
        int m = m0 + wm + mt * 16 + quad * 4 + r;
        int n = n0 + wn + nt * 16 + l16;
        float v = acc[mt][nt][r];
        if (FUSE) v += Dp[n] * b2f(Xr[(size_t)m * ldx + n]);
        st_out(Out + (size_t)m * ldo + n, v);
      }
    }
  }
}

// ---------------------------------------------------------------------------
// C0: fused cast fp32->bf16 for x (16M elems) and the 3 weights (1M each).
// ---------------------------------------------------------------------------
__global__ __launch_bounds__(256) void cast_all(
    const float* __restrict__ x, const float* __restrict__ dt_w,
    const float* __restrict__ B_w, const float* __restrict__ C_w,
    short* __restrict__ xb, short* __restrict__ wcat)
{
  size_t i = ((size_t)blockIdx.x * 256 + threadIdx.x) * 8;
  const size_t NX = (size_t)Mdim * Dd;           // 16,777,216
  const size_t NW = (size_t)Dd * Dd;             // 1,048,576
  if (i < NX) {
    *(short8*)(xb + i) = ld8f(x + i);
  } else {
    size_t j = i - NX;
    const float* src = (j < NW) ? (dt_w + j)
                     : (j < 2 * NW) ? (B_w + (j - NW))
                                    : (C_w + (j - 2 * NW));
    *(short8*)(wcat + j) = ld8f(src);
  }
}

// ---------------------------------------------------------------------------
// Gate/input: z = dt_pre + dt_b; sp = softplus(z); g = exp(sp*-exp(A_log));
// u = sp * Bp * x.
// ---------------------------------------------------------------------------
__device__ __forceinline__ void gate_in(float dtp, float db, float nA,
                                        float bp, float xv,
                                        float& g, float& u) {
  float z  = dtp + db;
  float sp = fmaxf(z, 0.f) + log1pf(expf(-fabsf(z)));
  g = expf(sp * nA);
  u = sp * bp * xv;
}

// ---------------------------------------------------------------------------
// S1: single transcendental pass. Per (b,c) chunk, thread owns 4 d.
// In-place over P: dt_pre slot <- hl(t) (running local scan, bf16),
//                  Bp slot     <- pg(t) (running gate prefix-product, bf16).
// fp32 running values stay in registers; stores are single-rounded.
// Chunk totals: Pc = prod(g) over chunk, Hl = local tail.
// ---------------------------------------------------------------------------
__global__ __launch_bounds__(256) void scan_local(
    short* __restrict__ P, const short* __restrict__ xb,
    const float* __restrict__ dt_b, const float* __restrict__ A_log,
    const float* __restrict__ h0,
    float* __restrict__ Pc, float* __restrict__ Hl)
{
  const int b  = blockIdx.x >> 7;
  const int c  = blockIdx.x & 127;
  const int d0 = threadIdx.x * 4;

  floatx4 db = *(const floatx4*)(dt_b + d0);
  floatx4 al = *(const floatx4*)(A_log + d0);
  float nA[4], p[4] = {1.f, 1.f, 1.f, 1.f}, h[4] = {};
#pragma unroll
  for (int j = 0; j < 4; j++) nA[j] = -expf(al[j]);

  const size_t mrow = (size_t)b * Sdim + (size_t)c * LCH;
  for (int t = 0; t < LCH; t++) {
    size_t m = mrow + t;
    short4v dt4 = *(const short4v*)(P + m * 2048 + d0);
    short4v bp4 = *(const short4v*)(P + m * 2048 + 1024 + d0);
    short4v xv4 = *(const short4v*)(xb + m * Dd + d0);
    short4v hl4, pg4;
#pragma unroll
    for (int j = 0; j < 4; j++) {
      float g, u;
      gate_in(b2f(dt4[j]), db[j], nA[j], b2f(bp4[j]), b2f(xv4[j]), g, u);
      if (c == 0 && t == 0) u += g * h0[b * Dd + d0 + j];
      h[j] = g * h[j] + u;
      p[j] *= g;
      hl4[j] = f2b(h[j]);
      pg4[j] = f2b(p[j]);
    }
    *(short4v*)(P + m * 2048 + d0)        = hl4;   // own addrs: safe in-place
    *(short4v*)(P + m * 2048 + 1024 + d0) = pg4;
  }
  size_t o = ((size_t)b * CCH + c) * Dd + d0;
  *(floatx4*)(Pc + o) = floatx4{p[0], p[1], p[2], p[3]};
  *(floatx4*)(Hl + o) = floatx4{h[0], h[1], h[2], h[3]};
}

// ---------------------------------------------------------------------------
// S2: sequential carry over 128 chunks; carry-in overwrites Pc.
// 1024 threads, float4 per thread.
// ---------------------------------------------------------------------------
__global__ __launch_bounds__(256) void scan_carry4(
    float* __restrict__ Pc, const float* __restrict__ Hl)
{
  const int t  = blockIdx.x * 256 + threadIdx.x;   // 0..1023
  const int b  = t >> 8;
  const int d0 = (t & 255) * 4;
  floatx4 st = {};
  for (int c = 0; c < CCH; c++) {
    size_t o = ((size_t)b * CCH + c) * Dd + d0;
    floatx4 pv = *(const floatx4*)(Pc + o);
    floatx4 hv = *(const floatx4*)(Hl + o);
    *(floatx4*)(Pc + o) = st;
    st = pv * st + hv;
  }
}

// ---------------------------------------------------------------------------
// S3: chain-free fixup: h(t) = hl(t) + carry * pg(t); h -> gate slot of P.
// Pure BW: 64MB read + 2MB carry + 32MB write.
// ---------------------------------------------------------------------------
__global__ __launch_bounds__(256) void scan_fix(
    short* __restrict__ P, const float* __restrict__ carry)
{
  size_t idx = ((size_t)blockIdx.x * 256 + threadIdx.x) * 4;  // over 16M elems
  const int m  = (int)(idx >> 10);
  const int d0 = (int)(idx & 1023);
  const int b  = m >> 12;
  const int c  = (m & (Sdim - 1)) >> 5;      // s / LCH
  short4v hl4 = *(const short4v*)(P + (size_t)m * 2048 + d0);
  short4v pg4 = *(const short4v*)(P + (size_t)m * 2048 + 1024 + d0);
  floatx4 cv  = *(const floatx4*)(carry + ((size_t)b * CCH + c) * Dd + d0);
  short4v o4;
#pragma unroll
  for (int j = 0; j < 4; j++)
    o4[j] = f2b(b2f(hl4[j]) + cv[j] * b2f(pg4[j]));
  *(short4v*)(P + (size_t)m * 2048 + d0) = o4;
}

// ---------------------------------------------------------------------------
extern "C" void kernel_launch(void* const* d_in, const int* in_sizes, int n_in,
                              void* d_out, int out_size, void* d_ws, size_t ws_size,
                              hipStream_t stream)
{
  const float* x     = (const float*)d_in[0];  // [4,4096,1024] fp32
  const float* h0    = (const float*)d_in[1];  // [4,1024]
  const float* dt_w  = (const float*)d_in[2];  // [1024,1024]
  const float* dt_b  = (const float*)d_in[3];  // [1024]
  const float* A_log = (const float*)d_in[4];  // [1024]
  const float* B_w   = (const float*)d_in[5];  // [1024,1024]
  const float* C_w   = (const float*)d_in[6];  // [1024,1024]
  const float* Dp    = (const float*)d_in[7];  // [1024]
  float* out = (float*)d_out;                  // [4,4096,1024] fp32

  // ws layout (106 MB, same bound as R4-proven):
  //   [0,64)    P bf16 [16384][2048]: dt_pre|Bp -> hl|pg -> h|pg
  //   [64,96)   xb bf16 [16384][1024]
  //   [96,102)  wcat bf16 [3072][1024]  (dt_w | B_w | C_w)
  //   [102,104) Pc fp32 [4][128][1024]  (chunk products, then carries)
  //   [104,106) Hl fp32 [4][128][1024]  (chunk local tails)
  char* ws = (char*)d_ws;
  short* P    = (short*)(ws);
  short* xb   = (short*)(ws + (64ull  << 20));
  short* wcat = (short*)(ws + (96ull  << 20));
  float* Pc   = (float*)(ws + (102ull << 20));
  float* Hl   = (float*)(ws + (104ull << 20));

  // C0: all casts in one launch: (16M + 3M)/8/256 = 9728 blocks
  cast_all<<<9728, 256, 0, stream>>>(x, dt_w, B_w, C_w, xb, wcat);

  // K1: P = x @ [dt_w;B_w]^T  (M=16384, N=2048, K=1024)
  gemm_async<short, false><<<dim3(Mdim / 128, 16), 256, 0, stream>>>(
      xb, Dd, wcat, P, 2048, 1024, nullptr, nullptr, 0);

  // S1-S3: chunked scan, transcendentals once, fixup chain-free
  scan_local<<<Bdim * CCH, 256, 0, stream>>>(P, xb, dt_b, A_log, h0, Pc, Hl);
  scan_carry4<<<4, 256, 0, stream>>>(Pc, Hl);
  scan_fix<<<(Mdim * Dd / 4) / 256, 256, 0, stream>>>(P, Pc);

  // K6: out = h @ C_w^T + D*x  (h bf16 in P lda=2048; D*x epilogue from xb)
  gemm_async<float, true><<<dim3(Mdim / 128, 8), 256, 0, stream>>>(
      P, 2048, wcat + 2 * 1024 * 1024, out, Dd, 1024, Dp, xb, Dd);
}